// Round 1
// baseline (9.305 us; speedup 1.0000x reference)
//
#include <hip/hip_runtime.h>
#include <math.h>

// Closed-form solution via Heisenberg picture.
//
// Circuit: RY(x_i) encoding on |0..0>, CNOT chain (i -> i+1, i=0..14),
// Rot(0.1, 0.2, 0.3) on every wire, measure <Z_i>.
//
// Heisenberg evolution of Z_i:
//   Rot† Z Rot = cosθ Z − sinθcosφ X + sinθsinφ Y           (ω drops out)
//   CNOT chain: Z_i → Z_0..Z_i ;  X_i → X_i X_{i+1} (X_15 → X_15) ;
//               Y_i → (Z_0..Z_{i-1}) Y_i X_{i+1}
// Product state ⟨Z_k⟩=cos x_k, ⟨X_k⟩=sin x_k, ⟨Y_k⟩=0 (real amplitudes),
// so the Y-term vanishes and:
//   out[b][i] = cosθ·Π_{k≤i} cos(x_bk)
//             + (−sinθ cosφ)·sin(x_bi)·(i<15 ? sin(x_b,i+1) : 1)

#define NQ 16

__global__ __launch_bounds__(64) void qlayer_closed_form(
    const float* __restrict__ x, float* __restrict__ out, int B) {
    int b = blockIdx.x * blockDim.x + threadIdx.x;
    if (b >= B) return;

    // cos(0.2) and -sin(0.2)*cos(0.1), double-precision host-math values
    const float D  = 0.98006657784124163f;
    const float Bc = -0.19767681165408385f;

    // 16 floats per row = 4 x float4 vector loads
    const float4* xp = reinterpret_cast<const float4*>(x) + (size_t)b * 4;
    float xs[NQ];
#pragma unroll
    for (int j = 0; j < 4; ++j) {
        float4 v = xp[j];
        xs[4 * j + 0] = v.x; xs[4 * j + 1] = v.y;
        xs[4 * j + 2] = v.z; xs[4 * j + 3] = v.w;
    }

    float c[NQ], s[NQ];
#pragma unroll
    for (int i = 0; i < NQ; ++i) {
        // |x| ~ N(0,1); sincosf accuracy vastly exceeds the 2e-2 threshold
        __sincosf(xs[i], &s[i], &c[i]);
    }

    float o[NQ];
    float pref = 1.0f;
#pragma unroll
    for (int i = 0; i < NQ; ++i) {
        pref *= c[i];                       // Π_{k≤i} cos(x_k)
        float snext = (i < NQ - 1) ? s[i + 1] : 1.0f;
        o[i] = D * pref + Bc * s[i] * snext;
    }

    float4* op = reinterpret_cast<float4*>(out) + (size_t)b * 4;
#pragma unroll
    for (int j = 0; j < 4; ++j) {
        op[j] = make_float4(o[4 * j + 0], o[4 * j + 1],
                            o[4 * j + 2], o[4 * j + 3]);
    }
}

extern "C" void kernel_launch(void* const* d_in, const int* in_sizes, int n_in,
                              void* d_out, int out_size, void* d_ws, size_t ws_size,
                              hipStream_t stream) {
    const float* x = (const float*)d_in[0];
    float* out = (float*)d_out;
    int B = in_sizes[0] / NQ;               // 512
    int threads = 64;                        // one wave per block, 8 blocks
    int blocks = (B + threads - 1) / threads;
    qlayer_closed_form<<<blocks, threads, 0, stream>>>(x, out, B);
}